// Round 4
// baseline (11.502 us; speedup 1.0000x reference)
//
#include <hip/hip_runtime.h>
#include <climits>

// Problem constants (match reference)
#define LROW 512
#define OUT_S 65
#define NOUT (OUT_S * OUT_S)   // 4225
#define THRESH 0.2f
#define EPS_F 1e-6f

typedef float f4 __attribute__((ext_vector_type(4)));

// 4 blocks per (n,c) row (grid = rows*4 = 1024 -> 4 blocks/CU for overlap).
// Every block redundantly computes full-row stats (loads are cache-hits;
// the reduction is the serial critical path we want to hide via overlap),
// then stores only its quarter of the 65x65 RP matrix.
// Zero __syncthreads(): per-wave butterfly + per-wave private xn[] in LDS.
__global__ __launch_bounds__(256) void rp_kernel(const float* __restrict__ x,
                                                 float* __restrict__ out) {
    const int bid  = blockIdx.x;
    const int row  = bid >> 2;         // 0 .. N*C-1
    const int q    = bid & 3;          // quarter of the output matrix
    const int tid  = threadIdx.x;      // 0 .. 255
    const int lane = tid & 63;
    const int wid  = tid >> 6;
    const float* xr = x + (size_t)row * LROW;
    const f4* xr4   = reinterpret_cast<const f4*>(xr);   // row base 2KB-aligned

    // ---- each wave loads the full row: 8 floats/lane (2x dwordx4) ----
    const f4 a = xr4[lane];        // x[4*lane .. 4*lane+3]
    const f4 b = xr4[lane + 64];   // x[256+4*lane .. +3]

    // ---- local stats over 8 elements ----
    int lo = INT_MAX, hi = -1;
    double s1 = 0.0, s2 = 0.0;
    #pragma unroll
    for (int e = 0; e < 4; ++e) {
        const int   k0 = 4 * lane + e;
        const float va = a[e];
        if (va != 0.0f) { lo = min(lo, k0); hi = max(hi, k0); }
        s1 += (double)va; s2 += (double)va * (double)va;
        const int   k1 = k0 + 256;
        const float vb = b[e];
        if (vb != 0.0f) { lo = min(lo, k1); hi = max(hi, k1); }
        s1 += (double)vb; s2 += (double)vb * (double)vb;
    }

    // ---- wave butterfly (no barriers; identical result in every wave) ----
    #pragma unroll
    for (int off = 32; off > 0; off >>= 1) {
        lo = min(lo, __shfl_xor(lo, off, 64));
        hi = max(hi, __shfl_xor(hi, off, 64));
        s1 += __shfl_xor(s1, off, 64);
        s2 += __shfl_xor(s2, off, 64);
    }

    const bool   anyNZ = (hi >= 0);
    const double cnt   = anyNZ ? (double)(hi - lo + 1) : 1.0;
    const float  mean  = (float)(s1 / cnt);          // fp32 mean, like reference
    const double dm    = (double)mean;
    double var = (s2 - 2.0 * dm * s1 + cnt * dm * dm) / cnt;
    var = var > 0.0 ? var : 0.0;                     // guard tiny negative rounding
    const float stdc = fmaxf(sqrtf((float)var), EPS_F);

    // ---- per-wave private xn[65] (padded): lanes 0..16 own x[0..67] ----
    __shared__ float xnw[4][68];                     // 16B-aligned rows
    if (lane < 17) {
        f4 w;
        #pragma unroll
        for (int e = 0; e < 4; ++e) {
            const int  k = 4 * lane + e;
            const bool m = anyNZ && (k >= lo) && (k <= hi);
            w[e] = m ? (a[e] - mean) / stdc : 0.0f;  // fp32 ops, like reference
        }
        *reinterpret_cast<f4*>(&xnw[wid][4 * lane]) = w;
    }
    // same-wave LDS RAW: drain lgkm before lanes read their wave's copy
    asm volatile("s_waitcnt lgkmcnt(0)" ::: "memory");

    const float* xn = xnw[wid];
    float* orow = out + (size_t)row * NOUT;

    // ---- this block's output slice: RP rows [rstart, rend) ----
    const int rstart = (q == 0) ? 0 : (16 * q + 1);          // 0,17,33,49
    const int rend   = rstart + ((q == 0) ? 17 : 16);        // 17,33,49,65
    const int e0 = rstart * OUT_S;
    const int e1 = rend * OUT_S;

    // alignment: global element index row*NOUT + e; out base is 256B-aligned
    const int mis = (int)(((size_t)row * NOUT + (size_t)e0) & 3);
    int h = (4 - mis) & 3;
    if (h > e1 - e0) h = e1 - e0;
    const int bstart = e0 + h;
    const int nbody  = (e1 - bstart) >> 2;
    const int t0     = bstart + (nbody << 2);
    const int ntail  = e1 - t0;                              // 0..3

    if (tid < h) {                                           // head scalars
        const int k = e0 + tid;
        const int i = k / OUT_S;
        const int j = k - i * OUT_S;
        orow[k] = (fabsf(xn[i] - xn[j]) < THRESH) ? 1.0f : 0.0f;
    }
    if (tid >= 8 && tid - 8 < ntail) {                       // tail scalars
        const int k = t0 + (tid - 8);
        const int i = k / OUT_S;
        const int j = k - i * OUT_S;
        orow[k] = (fabsf(xn[i] - xn[j]) < THRESH) ? 1.0f : 0.0f;
    }

    // body: aligned dwordx4 stores, <=2 iterations/thread
    for (int g = tid; g < nbody; g += 256) {
        const int es = bstart + 4 * g;
        const int i  = es / OUT_S;                           // magic-mul division
        int   jj  = es - i * OUT_S;
        float xii = xn[i];
        f4 r;
        #pragma unroll
        for (int e = 0; e < 4; ++e) {
            if (jj == OUT_S) { jj = 0; xii = xn[i + 1]; }    // row wrap (<=1/group)
            r[e] = (fabsf(xii - xn[jj]) < THRESH) ? 1.0f : 0.0f;
            ++jj;
        }
        *reinterpret_cast<f4*>(orow + es) = r;               // 16B-aligned
    }
}

extern "C" void kernel_launch(void* const* d_in, const int* in_sizes, int n_in,
                              void* d_out, int out_size, void* d_ws, size_t ws_size,
                              hipStream_t stream) {
    const float* x  = (const float*)d_in[0];
    float*      out = (float*)d_out;
    const int rows  = in_sizes[0] / LROW;   // 64*4 = 256
    rp_kernel<<<rows * 4, 256, 0, stream>>>(x, out);
}